// Round 1
// baseline (272.834 us; speedup 1.0000x reference)
//
#include <hip/hip_runtime.h>
#include <math.h>

#define BB 8
#define SS 128
#define NN 129
#define DD 256
#define HH 8
#define HD 32
#define LN_EPS 1e-5f

// ws layout (float offsets)
#define OFF_A    0        // a:     [B][S][D]  262144
#define OFF_BPT  262144   // bp_t:  [B][D][S]  262144  (b_ + b_e1, transposed)
#define OFF_CPT  524288   // cp_t:  [B][D][S]  262144  (a + b_ + b_e1, transposed)
#define OFF_VART 786432   // var_t: [B][D][S]  262144  (nv[:,1:,:] transposed)
#define OFF_V    1048576  // v:     [B][N][D]  264192
#define OFF_SQ   1312768  // sq:    [B][H][N]  8256
#define OFF_SK   1321024  // sk:    [B][H][N]  8256
#define OFF_NA   1329280  // na:    [B][N][N]  133128
#define OFF_MA   1462408  // [B*S] row means / second moments
#define OFF_QA   1463432
#define OFF_MB   1464456
#define OFF_QB   1465480
#define OFF_MC   1466504
#define OFF_QC   1467528
#define OFF_U    1468552  // U: [D][H] 2048
#define OFF_UB   1470600  // ubias: [H] 8
#define OFF_G    1470608  // G: [B][S][S] 131072
// total = 1601680 floats = 6.4 MB of ws

// ---------------- K0: fold W_e2/we -> U, b_e2/we -> ubias ----------------
__global__ void k0_pre(const float* __restrict__ W_e2, const float* __restrict__ b_e2,
                       const float* __restrict__ w_attn, float* __restrict__ U,
                       float* __restrict__ ubias) {
    int t = threadIdx.x;  // t == d
    const float* we = w_attn + 2 * HD;
#pragma unroll
    for (int h = 0; h < HH; h++) {
        float s = 0.f;
        for (int q = 0; q < HD; q++) s += W_e2[t * DD + h * HD + q] * we[q];
        U[t * HH + h] = s;
    }
    if (t < HH) {
        float s = 0.f;
        for (int q = 0; q < HD; q++) s += b_e2[t * HD + q] * we[q];
        ubias[t] = s;
    }
}

// ---------------- K1: d = desc@W_gt+b_gt; a = d@We1_top; b_ = d@We1_bot + b_e1;
//                      row stats + transposed stores + nv transpose ----------
__global__ __launch_bounds__(256) void k1_rows(
    const float* __restrict__ desc, const float* __restrict__ nv,
    const float* __restrict__ W_gt, const float* __restrict__ b_gt,
    const float* __restrict__ W_e1, const float* __restrict__ b_e1,
    float* __restrict__ a, float* __restrict__ bp_t, float* __restrict__ cp_t,
    float* __restrict__ var_t,
    float* __restrict__ ma, float* __restrict__ qa, float* __restrict__ mb,
    float* __restrict__ qb, float* __restrict__ mc, float* __restrict__ qc) {
    const int b = blockIdx.y, s0 = blockIdx.x * 4, t = threadIdx.x;
    __shared__ float dsc[4][DD];
    __shared__ float drow[4][DD];
    __shared__ float part[24][4];
#pragma unroll
    for (int r = 0; r < 4; r++) dsc[r][t] = desc[(size_t)(b * SS + s0 + r) * DD + t];
    __syncthreads();
    float dv[4];
    float bgt = b_gt[t];
#pragma unroll
    for (int r = 0; r < 4; r++) dv[r] = bgt;
    for (int k = 0; k < DD; k++) {
        float w = W_gt[k * DD + t];
#pragma unroll
        for (int r = 0; r < 4; r++) dv[r] += dsc[r][k] * w;
    }
#pragma unroll
    for (int r = 0; r < 4; r++) drow[r][t] = dv[r];
    __syncthreads();
    float av[4] = {0, 0, 0, 0}, bv[4] = {0, 0, 0, 0};
    for (int k = 0; k < DD; k++) {
        float wa = W_e1[k * DD + t];
        float wb = W_e1[(DD + k) * DD + t];
#pragma unroll
        for (int r = 0; r < 4; r++) { float dk = drow[r][k]; av[r] += dk * wa; bv[r] += dk * wb; }
    }
    float be1 = b_e1[t];
    float cv[4];
#pragma unroll
    for (int r = 0; r < 4; r++) { bv[r] += be1; cv[r] = av[r] + bv[r]; }
#pragma unroll
    for (int r = 0; r < 4; r++) a[(size_t)(b * SS + s0 + r) * DD + t] = av[r];
    float4 f4;
    f4.x = bv[0]; f4.y = bv[1]; f4.z = bv[2]; f4.w = bv[3];
    *(float4*)(bp_t + (size_t)(b * DD + t) * SS + s0) = f4;
    f4.x = cv[0]; f4.y = cv[1]; f4.z = cv[2]; f4.w = cv[3];
    *(float4*)(cp_t + (size_t)(b * DD + t) * SS + s0) = f4;
    float nvv[4];
#pragma unroll
    for (int r = 0; r < 4; r++) nvv[r] = nv[(size_t)(b * NN + 1 + s0 + r) * DD + t];
    f4.x = nvv[0]; f4.y = nvv[1]; f4.z = nvv[2]; f4.w = nvv[3];
    *(float4*)(var_t + (size_t)(b * DD + t) * SS + s0) = f4;
    // 24 block reductions (4 rows x {sumA,sumA2,sumB,sumB2,sumC,sumC2})
    float vals[24];
#pragma unroll
    for (int r = 0; r < 4; r++) {
        vals[r * 6 + 0] = av[r]; vals[r * 6 + 1] = av[r] * av[r];
        vals[r * 6 + 2] = bv[r]; vals[r * 6 + 3] = bv[r] * bv[r];
        vals[r * 6 + 4] = cv[r]; vals[r * 6 + 5] = cv[r] * cv[r];
    }
    int lane = t & 63, wid = t >> 6;
#pragma unroll
    for (int v = 0; v < 24; v++) {
        float x = vals[v];
        for (int o = 32; o; o >>= 1) x += __shfl_xor(x, o, 64);
        if (lane == 0) part[v][wid] = x;
    }
    __syncthreads();
    if (t < 24) {
        float ssum = (part[t][0] + part[t][1]) + (part[t][2] + part[t][3]);
        int r = t / 6, st = t % 6;
        int row = b * SS + s0 + r;
        float m = ssum * (1.f / DD);
        float* dstp = (st == 0) ? ma : (st == 1) ? qa : (st == 2) ? mb
                     : (st == 3) ? qb : (st == 4) ? mc : qc;
        dstp[row] = m;
    }
}

// ---------------- K2: v projection + per-head collapsed q/k scores ----------
__global__ __launch_bounds__(256) void k2_qkv(
    const float* __restrict__ nv,
    const float* __restrict__ W_q, const float* __restrict__ b_q,
    const float* __restrict__ W_k, const float* __restrict__ b_k,
    const float* __restrict__ W_v, const float* __restrict__ b_v,
    const float* __restrict__ w_attn,
    float* __restrict__ v, float* __restrict__ sq, float* __restrict__ sk) {
    const int b = blockIdx.y, n0 = blockIdx.x * 4, t = threadIdx.x;
    __shared__ float row[4][DD];
#pragma unroll
    for (int r = 0; r < 4; r++) {
        int n = n0 + r; int nc = n < NN ? n : NN - 1;
        row[r][t] = nv[(size_t)(b * NN + nc) * DD + t];
    }
    __syncthreads();
    float qv[4], kv[4], vv[4];
    float bq = b_q[t], bk = b_k[t], bvb = b_v[t];
#pragma unroll
    for (int r = 0; r < 4; r++) { qv[r] = bq; kv[r] = bk; vv[r] = bvb; }
    for (int k = 0; k < DD; k++) {
        float wq = W_q[k * DD + t], wk = W_k[k * DD + t], wv = W_v[k * DD + t];
#pragma unroll
        for (int r = 0; r < 4; r++) { float x = row[r][k]; qv[r] += x * wq; kv[r] += x * wk; vv[r] += x * wv; }
    }
    float waq = w_attn[t & (HD - 1)];
    float wak = w_attn[HD + (t & (HD - 1))];
    int h = t >> 5;
#pragma unroll
    for (int r = 0; r < 4; r++) {
        int n = n0 + r;
        if (n < NN) v[(size_t)(b * NN + n) * DD + t] = vv[r];
        float xq = qv[r] * waq, xk = kv[r] * wak;
#pragma unroll
        for (int o = 16; o; o >>= 1) { xq += __shfl_xor(xq, o, 64); xk += __shfl_xor(xk, o, 64); }
        if ((t & 31) == 0 && n < NN) { sq[(b * HH + h) * NN + n] = xq; sk[(b * HH + h) * NN + n] = xk; }
    }
}

// ---------------- K3: cross-term GEMM G = a @ bp^T and adjacency mask -------
__global__ __launch_bounds__(128) void k3_adj(
    const float* __restrict__ a, const float* __restrict__ bp_t,
    const float* __restrict__ nv, const float* __restrict__ var_t,
    float* __restrict__ G, float* __restrict__ na) {
    const int b = blockIdx.y, ii0 = blockIdx.x * 2, j = threadIdx.x;
    __shared__ float arw[2][DD];
    __shared__ float vrw[2][DD];
    for (int idx = j; idx < 2 * DD; idx += 128) {
        int il = idx >> 8, d = idx & 255;
        arw[il][d] = a[(size_t)(b * SS + ii0 + il) * DD + d];
        vrw[il][d] = nv[(size_t)(b * NN + 1 + ii0 + il) * DD + d];
    }
    __syncthreads();
    float dg[2] = {0, 0}, dvv[2] = {0, 0};
    const float* bc = bp_t + (size_t)b * DD * SS + j;
    const float* vc = var_t + (size_t)b * DD * SS + j;
#pragma unroll 4
    for (int d = 0; d < DD; d++) {
        float bb = bc[(size_t)d * SS];
        float vv = vc[(size_t)d * SS];
#pragma unroll
        for (int il = 0; il < 2; il++) { dg[il] += arw[il][d] * bb; dvv[il] += vrw[il][d] * vv; }
    }
#pragma unroll
    for (int il = 0; il < 2; il++) {
        int ii = ii0 + il;
        G[(size_t)(b * SS + ii) * SS + j] = dg[il];
        na[(size_t)(b * NN + ii + 1) * NN + (j + 1)] = (ii != j && dvv[il] > 0.f) ? 1.f : 0.f;
        if (j == 0) na[(size_t)(b * NN + ii + 1) * NN] = 0.f;
    }
    if (ii0 == 0) {
        na[(size_t)(b * NN) * NN + (j + 1)] = 1.f;
        if (j == 0) na[(size_t)(b * NN) * NN] = 0.f;
    }
}

// ---------------- K4: fused LN(closed-form stats) + relu + U-dot + scores ---
__global__ __launch_bounds__(128) void k4_scores(
    const float* __restrict__ a, const float* __restrict__ bp_t, const float* __restrict__ cp_t,
    const float* __restrict__ ma, const float* __restrict__ qa,
    const float* __restrict__ mb, const float* __restrict__ qb,
    const float* __restrict__ mc, const float* __restrict__ qc,
    const float* __restrict__ G, const float* __restrict__ na,
    const float* __restrict__ sq, const float* __restrict__ sk,
    const float* __restrict__ ln_g, const float* __restrict__ ln_b,
    const float* __restrict__ U, const float* __restrict__ ubias,
    const float* __restrict__ b_attn,
    float* __restrict__ attn) {
    const int b = blockIdx.y, i0 = blockIdx.x * 2, jt = threadIdx.x;  // jt = j-1
    __shared__ float Arow[2][DD];
    for (int idx = jt; idx < 2 * DD; idx += 128) {
        int il = idx >> 8, d = idx & 255;
        int i = i0 + il;
        Arow[il][d] = (i >= 1 && i < NN) ? a[(size_t)(b * SS + i - 1) * DD + d] : 0.f;
    }
    __syncthreads();
    float rs[2], nm[2], mk[2];
    bool useC[2];
#pragma unroll
    for (int il = 0; il < 2; il++) {
        int i = i0 + il; if (i > NN - 1) i = NN - 1;
        mk[il] = na[(size_t)(b * NN + i) * NN + jt + 1];
        float muA, qA, muB, qB, cross;
        if (i >= 1) {
            muA = ma[b * SS + i - 1]; qA = qa[b * SS + i - 1];
            muB = mb[b * SS + jt];    qB = qb[b * SS + jt];
            cross = G[(size_t)(b * SS + i - 1) * SS + jt];
            useC[il] = false;
        } else {
            muA = 0.f; qA = 0.f; muB = mc[b * SS + jt]; qB = qc[b * SS + jt];
            cross = 0.f; useC[il] = true;
        }
        float mu = muA + muB;
        float var = qA + qB + 2.f * cross * (1.f / DD) - mu * mu;
        float r = rsqrtf(var + LN_EPS);
        rs[il] = r; nm[il] = -mu * r;
    }
    const float* Bb = bp_t + (size_t)b * DD * SS + jt;
    const float* Bc = cp_t + (size_t)b * DD * SS + jt;
    const bool hasC = (i0 == 0);
    float acc[2][HH];
#pragma unroll
    for (int il = 0; il < 2; il++)
#pragma unroll
        for (int h = 0; h < HH; h++) acc[il][h] = 0.f;
#pragma unroll 4
    for (int d = 0; d < DD; d++) {
        float Bbv = Bb[(size_t)d * SS];
        float Bcv = hasC ? Bc[(size_t)d * SS] : 0.f;
        float g = ln_g[d], be = ln_b[d];
#pragma unroll
        for (int il = 0; il < 2; il++) {
            float Bv = useC[il] ? Bcv : Bbv;
            float pre = Arow[il][d] + Bv;
            float y = pre * rs[il] + nm[il];
            y = y * g + be;
            float rr = fmaxf(y, 0.f);
#pragma unroll
            for (int h = 0; h < HH; h++) acc[il][h] += rr * U[d * HH + h];
        }
    }
    const float ba = b_attn[0];
#pragma unroll
    for (int il = 0; il < 2; il++) {
        int i = i0 + il; if (i >= NN) continue;
        float m = mk[il];
        float pen = (m == 0.f) ? -1e9f : 0.f;
#pragma unroll
        for (int h = 0; h < HH; h++) {
            float ew = (acc[il][h] + ubias[h]) * m;  // reference: e *= na before we-dot
            float sc = sq[(b * HH + h) * NN + i] + sk[(b * HH + h) * NN + jt + 1] + ew + ba + pen;
            attn[((size_t)(b * HH + h) * NN + i) * NN + jt + 1] = sc;
        }
    }
    if (jt < 2) {  // j = 0 column: always masked, ew = 0 exactly
        int i = i0 + jt;
        if (i < NN) {
#pragma unroll
            for (int h = 0; h < HH; h++) {
                float sc = sq[(b * HH + h) * NN + i] + sk[(b * HH + h) * NN + 0] + ba - 1e9f;
                attn[((size_t)(b * HH + h) * NN + i) * NN] = sc;
            }
        }
    }
}

// ---------------- K5: in-place row softmax (wave per row, N=129) ------------
__global__ __launch_bounds__(256) void k5_softmax(float* __restrict__ attn) {
    int row = blockIdx.x * 4 + (threadIdx.x >> 6);
    int lane = threadIdx.x & 63;
    if (row >= BB * HH * NN) return;
    float* p = attn + (size_t)row * NN;
    float x0 = p[lane], x1 = p[lane + 64];
    float x2 = (lane == 0) ? p[128] : -INFINITY;
    float m = fmaxf(fmaxf(x0, x1), x2);
    for (int o = 32; o; o >>= 1) m = fmaxf(m, __shfl_xor(m, o, 64));
    float e0 = expf(x0 - m), e1 = expf(x1 - m);
    float e2 = (lane == 0) ? expf(x2 - m) : 0.f;
    float s = e0 + e1 + e2;
    for (int o = 32; o; o >>= 1) s += __shfl_xor(s, o, 64);
    float inv = 1.f / s;
    p[lane] = e0 * inv; p[lane + 64] = e1 * inv;
    if (lane == 0) p[128] = e2 * inv;
}

// ---------------- K6: ctx = attn@v, out = ctx@W_o + b_o ---------------------
__global__ __launch_bounds__(256) void k6_out(
    const float* __restrict__ attn, const float* __restrict__ v,
    const float* __restrict__ W_o, const float* __restrict__ b_o,
    float* __restrict__ out) {
    const int b = blockIdx.y, i0 = blockIdx.x * 4, t = threadIdx.x;
    __shared__ float ar[4][HH * NN];
    __shared__ float ctx2[DD][4];
#pragma unroll
    for (int il = 0; il < 4; il++) {
        int i = i0 + il; if (i >= NN) i = NN - 1;
        for (int idx = t; idx < HH * NN; idx += 256) {
            int h = idx / NN, j = idx - h * NN;
            ar[il][idx] = attn[((size_t)(b * HH + h) * NN + i) * NN + j];
        }
    }
    __syncthreads();
    int h = t >> 5;
    float acc[4] = {0, 0, 0, 0};
    for (int j = 0; j < NN; j++) {
        float vv = v[(size_t)(b * NN + j) * DD + t];
#pragma unroll
        for (int il = 0; il < 4; il++) acc[il] += ar[il][h * NN + j] * vv;
    }
#pragma unroll
    for (int il = 0; il < 4; il++) ctx2[t][il] = acc[il];
    __syncthreads();
    float bo = b_o[t];
    float o[4] = {bo, bo, bo, bo};
    for (int k = 0; k < DD; k++) {
        float w = W_o[k * DD + t];
        float4 c = *(const float4*)&ctx2[k][0];
        o[0] += c.x * w; o[1] += c.y * w; o[2] += c.z * w; o[3] += c.w * w;
    }
#pragma unroll
    for (int il = 0; il < 4; il++) {
        int i = i0 + il;
        if (i < NN) out[(size_t)(b * NN + i) * DD + t] = o[il];
    }
}

extern "C" void kernel_launch(void* const* d_in, const int* in_sizes, int n_in,
                              void* d_out, int out_size, void* d_ws, size_t ws_size,
                              hipStream_t stream) {
    const float* desc   = (const float*)d_in[0];
    const float* nv     = (const float*)d_in[1];
    const float* W_gt   = (const float*)d_in[2];
    const float* b_gt   = (const float*)d_in[3];
    // d_in[4] topo_bias: unused — sigmoid(x)>0 for all x, so sign(adj_mat)=sign(sample_sim)
    const float* W_q    = (const float*)d_in[5];
    const float* b_q    = (const float*)d_in[6];
    const float* W_k    = (const float*)d_in[7];
    const float* b_k    = (const float*)d_in[8];
    const float* W_v    = (const float*)d_in[9];
    const float* b_v    = (const float*)d_in[10];
    const float* W_e1   = (const float*)d_in[11];
    const float* b_e1   = (const float*)d_in[12];
    const float* ln_g   = (const float*)d_in[13];
    const float* ln_b   = (const float*)d_in[14];
    const float* W_e2   = (const float*)d_in[15];
    const float* b_e2   = (const float*)d_in[16];
    const float* w_attn = (const float*)d_in[17];
    const float* b_attn = (const float*)d_in[18];
    const float* W_o    = (const float*)d_in[19];
    const float* b_o    = (const float*)d_in[20];

    float* ws   = (float*)d_ws;
    float* a    = ws + OFF_A;
    float* bp_t = ws + OFF_BPT;
    float* cp_t = ws + OFF_CPT;
    float* vart = ws + OFF_VART;
    float* v    = ws + OFF_V;
    float* sq   = ws + OFF_SQ;
    float* sk   = ws + OFF_SK;
    float* na   = ws + OFF_NA;
    float* ma   = ws + OFF_MA;
    float* qa   = ws + OFF_QA;
    float* mb   = ws + OFF_MB;
    float* qb   = ws + OFF_QB;
    float* mc   = ws + OFF_MC;
    float* qc   = ws + OFF_QC;
    float* U    = ws + OFF_U;
    float* ub   = ws + OFF_UB;
    float* G    = ws + OFF_G;

    float* out  = (float*)d_out;
    float* attn = (float*)d_out + (size_t)BB * NN * DD;

    k0_pre<<<dim3(1), dim3(256), 0, stream>>>(W_e2, b_e2, w_attn, U, ub);
    k1_rows<<<dim3(SS / 4, BB), dim3(256), 0, stream>>>(
        desc, nv, W_gt, b_gt, W_e1, b_e1, a, bp_t, cp_t, vart, ma, qa, mb, qb, mc, qc);
    k2_qkv<<<dim3((NN + 3) / 4, BB), dim3(256), 0, stream>>>(
        nv, W_q, b_q, W_k, b_k, W_v, b_v, w_attn, v, sq, sk);
    k3_adj<<<dim3(SS / 2, BB), dim3(128), 0, stream>>>(a, bp_t, nv, vart, G, na);
    k4_scores<<<dim3((NN + 1) / 2, BB), dim3(128), 0, stream>>>(
        a, bp_t, cp_t, ma, qa, mb, qb, mc, qc, G, na, sq, sk, ln_g, ln_b, U, ub, b_attn, attn);
    k5_softmax<<<dim3((BB * HH * NN + 3) / 4), dim3(256), 0, stream>>>(attn);
    k6_out<<<dim3((NN + 3) / 4, BB), dim3(256), 0, stream>>>(attn, v, W_o, b_o, out);
}

// Round 2
// 257.251 us; speedup vs baseline: 1.0606x; 1.0606x over previous
//
#include <hip/hip_runtime.h>
#include <math.h>

#define BB 8
#define SS 128
#define NN 129
#define DD 256
#define HH 8
#define HD 32
#define LN_EPS 1e-5f

// ws layout (float offsets)
#define OFF_A    0        // a:     [B][S][D]  262144
#define OFF_BPT  262144   // bp_t:  [B][D][S]  262144  (b_ + b_e1, transposed)
#define OFF_CPT  524288   // cp_t:  [B][D][S]  262144  (a + b_ + b_e1, transposed)
#define OFF_VART 786432   // var_t: [B][D][S]  262144  (nv[:,1:,:] transposed)
#define OFF_V    1048576  // v:     [B][N][D]  264192
#define OFF_SQ   1312768  // sq:    [B][H][N]  8256
#define OFF_SK   1321024  // sk:    [B][H][N]  8256
#define OFF_MA   1329280  // [B*S] each
#define OFF_QA   1330304
#define OFF_MB   1331328
#define OFF_QB   1332352
#define OFF_MC   1333376
#define OFF_QC   1334400
#define OFF_U    1335424  // U: [D][H] 2048
#define OFF_UB   1337472  // ubias: [H] 8
// total ~1.34M floats = 5.35 MB

// ---------------- K0: fold W_e2/we -> U, b_e2/we -> ubias (8 blocks) -------
__global__ void k0_pre(const float* __restrict__ W_e2, const float* __restrict__ b_e2,
                       const float* __restrict__ w_attn, float* __restrict__ U,
                       float* __restrict__ ubias) {
    const int h = blockIdx.x, d = threadIdx.x;
    const float* we = w_attn + 2 * HD;
    float s = 0.f;
#pragma unroll
    for (int q = 0; q < HD; q++) s += W_e2[d * DD + h * HD + q] * we[q];
    U[d * HH + h] = s;
    if (h == 0 && d < HH) {
        float sb = 0.f;
#pragma unroll
        for (int q = 0; q < HD; q++) sb += b_e2[d * HD + q] * we[q];
        ubias[d] = sb;
    }
}

// ---------------- K1: d/a/b_ projections, split-k x4, stats, transposes -----
__global__ __launch_bounds__(1024) void k1_rows(
    const float* __restrict__ desc, const float* __restrict__ nv,
    const float* __restrict__ W_gt, const float* __restrict__ b_gt,
    const float* __restrict__ W_e1, const float* __restrict__ b_e1,
    float* __restrict__ a, float* __restrict__ bp_t, float* __restrict__ cp_t,
    float* __restrict__ var_t,
    float* __restrict__ ma, float* __restrict__ qa, float* __restrict__ mb,
    float* __restrict__ qb, float* __restrict__ mc, float* __restrict__ qc) {
    const int b = blockIdx.y, s0 = blockIdx.x * 4;
    const int t = threadIdx.x, d = t & 255, kh = t >> 8;
    __shared__ float dsc[4][DD];
    __shared__ float drow[4][DD];
    __shared__ float red[4][4][DD];
    __shared__ float red2[4][4][DD];
    __shared__ float part[24][4];
    dsc[kh][d] = desc[(size_t)(b * SS + s0 + kh) * DD + d];
    __syncthreads();
    {   // phase A: d = desc @ W_gt
        float dv0 = 0, dv1 = 0, dv2 = 0, dv3 = 0;
        const int kb = kh * 64;
        for (int k = kb; k < kb + 64; k++) {
            float w = W_gt[k * DD + d];
            dv0 += dsc[0][k] * w; dv1 += dsc[1][k] * w;
            dv2 += dsc[2][k] * w; dv3 += dsc[3][k] * w;
        }
        red[kh][0][d] = dv0; red[kh][1][d] = dv1; red[kh][2][d] = dv2; red[kh][3][d] = dv3;
    }
    __syncthreads();
    drow[kh][d] = red[0][kh][d] + red[1][kh][d] + red[2][kh][d] + red[3][kh][d] + b_gt[d];
    __syncthreads();
    {   // phase B: a = d @ We1_top ; b = d @ We1_bot
        float av[4] = {0, 0, 0, 0}, bv[4] = {0, 0, 0, 0};
        const int kb = kh * 64;
        for (int k = kb; k < kb + 64; k++) {
            float wa = W_e1[k * DD + d];
            float wb = W_e1[(DD + k) * DD + d];
            float d0 = drow[0][k], d1 = drow[1][k], d2 = drow[2][k], d3 = drow[3][k];
            av[0] += d0 * wa; av[1] += d1 * wa; av[2] += d2 * wa; av[3] += d3 * wa;
            bv[0] += d0 * wb; bv[1] += d1 * wb; bv[2] += d2 * wb; bv[3] += d3 * wb;
        }
#pragma unroll
        for (int r = 0; r < 4; r++) { red[kh][r][d] = av[r]; red2[kh][r][d] = bv[r]; }
    }
    __syncthreads();
    if (t < 256) {  // waves 0-3 finalize (wave-uniform branch)
        float avf[4], bvf[4], cvf[4];
        float be1 = b_e1[d];
#pragma unroll
        for (int r = 0; r < 4; r++) {
            avf[r] = red[0][r][d] + red[1][r][d] + red[2][r][d] + red[3][r][d];
            bvf[r] = red2[0][r][d] + red2[1][r][d] + red2[2][r][d] + red2[3][r][d] + be1;
            cvf[r] = avf[r] + bvf[r];
        }
#pragma unroll
        for (int r = 0; r < 4; r++) a[(size_t)(b * SS + s0 + r) * DD + d] = avf[r];
        float4 f4;
        f4.x = bvf[0]; f4.y = bvf[1]; f4.z = bvf[2]; f4.w = bvf[3];
        *(float4*)(bp_t + (size_t)(b * DD + d) * SS + s0) = f4;
        f4.x = cvf[0]; f4.y = cvf[1]; f4.z = cvf[2]; f4.w = cvf[3];
        *(float4*)(cp_t + (size_t)(b * DD + d) * SS + s0) = f4;
        float nvv[4];
#pragma unroll
        for (int r = 0; r < 4; r++) nvv[r] = nv[(size_t)(b * NN + 1 + s0 + r) * DD + d];
        f4.x = nvv[0]; f4.y = nvv[1]; f4.z = nvv[2]; f4.w = nvv[3];
        *(float4*)(var_t + (size_t)(b * DD + d) * SS + s0) = f4;
        float vals[24];
#pragma unroll
        for (int r = 0; r < 4; r++) {
            vals[r * 6 + 0] = avf[r]; vals[r * 6 + 1] = avf[r] * avf[r];
            vals[r * 6 + 2] = bvf[r]; vals[r * 6 + 3] = bvf[r] * bvf[r];
            vals[r * 6 + 4] = cvf[r]; vals[r * 6 + 5] = cvf[r] * cvf[r];
        }
        int lane = t & 63, wid = t >> 6;
#pragma unroll
        for (int v = 0; v < 24; v++) {
            float x = vals[v];
            for (int o = 32; o; o >>= 1) x += __shfl_xor(x, o, 64);
            if (lane == 0) part[v][wid] = x;
        }
    }
    __syncthreads();
    if (t < 24) {
        float ssum = (part[t][0] + part[t][1]) + (part[t][2] + part[t][3]);
        int st = t % 6;
        int row = b * SS + s0 + t / 6;
        float m = ssum * (1.f / DD);
        float* dstp = (st == 0) ? ma : (st == 1) ? qa : (st == 2) ? mb
                     : (st == 3) ? qb : (st == 4) ? mc : qc;
        dstp[row] = m;
    }
}

// ---------------- K2: v projection + collapsed q/k scores, split-k x4 -------
__global__ __launch_bounds__(1024) void k2_qkv(
    const float* __restrict__ nv,
    const float* __restrict__ W_q, const float* __restrict__ b_q,
    const float* __restrict__ W_k, const float* __restrict__ b_k,
    const float* __restrict__ W_v, const float* __restrict__ b_v,
    const float* __restrict__ w_attn,
    float* __restrict__ v, float* __restrict__ sq, float* __restrict__ sk) {
    const int b = blockIdx.y, n0 = blockIdx.x * 4;
    const int t = threadIdx.x, d = t & 255, kh = t >> 8;
    __shared__ float row[4][DD];
    __shared__ float redq[4][4][DD];
    __shared__ float redk[4][4][DD];
    __shared__ float redv[4][4][DD];
    {
        int n = n0 + kh; if (n >= NN) n = NN - 1;
        row[kh][d] = nv[(size_t)(b * NN + n) * DD + d];
    }
    __syncthreads();
    {
        float qv[4] = {0, 0, 0, 0}, kv[4] = {0, 0, 0, 0}, vv[4] = {0, 0, 0, 0};
        const int kb = kh * 64;
        for (int k = kb; k < kb + 64; k++) {
            float wq = W_q[k * DD + d], wk = W_k[k * DD + d], wv = W_v[k * DD + d];
            float r0 = row[0][k], r1 = row[1][k], r2 = row[2][k], r3 = row[3][k];
            qv[0] += r0 * wq; qv[1] += r1 * wq; qv[2] += r2 * wq; qv[3] += r3 * wq;
            kv[0] += r0 * wk; kv[1] += r1 * wk; kv[2] += r2 * wk; kv[3] += r3 * wk;
            vv[0] += r0 * wv; vv[1] += r1 * wv; vv[2] += r2 * wv; vv[3] += r3 * wv;
        }
#pragma unroll
        for (int r = 0; r < 4; r++) { redq[kh][r][d] = qv[r]; redk[kh][r][d] = kv[r]; redv[kh][r][d] = vv[r]; }
    }
    __syncthreads();
    if (t < 256) {
        float bq = b_q[d], bk = b_k[d], bvb = b_v[d];
        float waq = w_attn[d & (HD - 1)];
        float wak = w_attn[HD + (d & (HD - 1))];
        int h = d >> 5;
#pragma unroll
        for (int r = 0; r < 4; r++) {
            float qf = redq[0][r][d] + redq[1][r][d] + redq[2][r][d] + redq[3][r][d] + bq;
            float kf = redk[0][r][d] + redk[1][r][d] + redk[2][r][d] + redk[3][r][d] + bk;
            float vf = redv[0][r][d] + redv[1][r][d] + redv[2][r][d] + redv[3][r][d] + bvb;
            int n = n0 + r;
            if (n < NN) v[(size_t)(b * NN + n) * DD + d] = vf;
            float xq = qf * waq, xk = kf * wak;
#pragma unroll
            for (int o = 16; o; o >>= 1) { xq += __shfl_xor(xq, o, 64); xk += __shfl_xor(xk, o, 64); }
            if ((d & 31) == 0 && n < NN) { sq[(b * HH + h) * NN + n] = xq; sk[(b * HH + h) * NN + n] = xk; }
        }
    }
}

// ---------------- K4m: adjacency + cross + LN + relu + U-dot + scores + softmax
__global__ __launch_bounds__(256) void k4_mega(
    const float* __restrict__ a, const float* __restrict__ bp_t, const float* __restrict__ cp_t,
    const float* __restrict__ var_t, const float* __restrict__ nv,
    const float* __restrict__ ma, const float* __restrict__ qa,
    const float* __restrict__ mb, const float* __restrict__ qb,
    const float* __restrict__ mc, const float* __restrict__ qc,
    const float* __restrict__ sq, const float* __restrict__ sk,
    const float* __restrict__ ln_g, const float* __restrict__ ln_b,
    const float* __restrict__ U, const float* __restrict__ ubias,
    const float* __restrict__ b_attn,
    float* __restrict__ attn) {
    const int b = blockIdx.y, i = blockIdx.x;
    const int t = threadIdx.x, jt = t & 127, dh = t >> 7;
    __shared__ float Arow[DD];
    __shared__ float Vrow[DD];
    __shared__ float redc[128][2];
    __shared__ float redvv[128][2];
    __shared__ float reda[128][9];
    __shared__ float sc[HH][NN + 3];
    Arow[t] = (i >= 1) ? a[(size_t)(b * SS + i - 1) * DD + t] : 0.f;
    Vrow[t] = nv[(size_t)(b * NN + i) * DD + t];
    __syncthreads();
    // pass 1: cross = a_i . b'_j ; dvv = nv_i . nv_j  (adjacency sign)
    float cross = 0.f, dvv = 0.f;
    if (i >= 1) {
        const float* bc = bp_t + ((size_t)b * DD + dh * 128) * SS + jt;
        const float* vc = var_t + ((size_t)b * DD + dh * 128) * SS + jt;
#pragma unroll 4
        for (int dd = 0; dd < 128; dd++) {
            cross += Arow[dh * 128 + dd] * bc[(size_t)dd * SS];
            dvv   += Vrow[dh * 128 + dd] * vc[(size_t)dd * SS];
        }
    }
    redc[jt][dh] = cross; redvv[jt][dh] = dvv;
    __syncthreads();
    cross = redc[jt][0] + redc[jt][1];
    dvv   = redvv[jt][0] + redvv[jt][1];
    float mk, rs, nm;
    {
        float muA, qA, muB, qB;
        if (i >= 1) {
            muA = ma[b * SS + i - 1]; qA = qa[b * SS + i - 1];
            muB = mb[b * SS + jt];    qB = qb[b * SS + jt];
            mk = ((i - 1) != jt && dvv > 0.f) ? 1.f : 0.f;
        } else {
            muA = 0.f; qA = 0.f; muB = mc[b * SS + jt]; qB = qc[b * SS + jt];
            cross = 0.f; mk = 1.f;
        }
        float mu = muA + muB;
        float var = qA + qB + 2.f * cross * (1.f / DD) - mu * mu;
        rs = rsqrtf(var + LN_EPS);
        nm = -mu * rs;
    }
    // pass 2: elementwise LN + relu + 8-head U dot
    float acc[HH];
#pragma unroll
    for (int h = 0; h < HH; h++) acc[h] = 0.f;
    {
        const float* Bc = ((i == 0) ? cp_t : bp_t) + ((size_t)b * DD + dh * 128) * SS + jt;
#pragma unroll 2
        for (int dd = 0; dd < 128; dd++) {
            int dfull = dh * 128 + dd;
            float pre = Arow[dfull] + Bc[(size_t)dd * SS];
            float y = fmaf(pre, rs, nm);
            y = fmaf(y, ln_g[dfull], ln_b[dfull]);
            float rr = fmaxf(y, 0.f);
#pragma unroll
            for (int h = 0; h < HH; h++) acc[h] += rr * U[dfull * HH + h];
        }
    }
    if (dh == 1) {
#pragma unroll
        for (int h = 0; h < HH; h++) reda[jt][h] = acc[h];
    }
    __syncthreads();
    if (dh == 0) {
        const float ba = b_attn[0];
        float pen = (mk == 0.f) ? -1e9f : 0.f;
#pragma unroll
        for (int h = 0; h < HH; h++) {
            float af = acc[h] + reda[jt][h];
            float ew = (af + ubias[h]) * mk;
            sc[h][jt + 1] = sq[(b * HH + h) * NN + i] + sk[(b * HH + h) * NN + jt + 1] + ew + ba + pen;
        }
        if (jt == 0) {
#pragma unroll
            for (int h = 0; h < HH; h++)
                sc[h][0] = sq[(b * HH + h) * NN + i] + sk[(b * HH + h) * NN] + ba - 1e9f;
        }
    }
    __syncthreads();
    // softmax: h per 32-lane group
    {
        int h = t >> 5, l = t & 31;
        float m = -INFINITY;
        for (int j = l; j < NN; j += 32) m = fmaxf(m, sc[h][j]);
#pragma unroll
        for (int o = 16; o; o >>= 1) m = fmaxf(m, __shfl_xor(m, o, 32));
        float s = 0.f;
        for (int j = l; j < NN; j += 32) { float e = __expf(sc[h][j] - m); sc[h][j] = e; s += e; }
#pragma unroll
        for (int o = 16; o; o >>= 1) s += __shfl_xor(s, o, 32);
        float inv = 1.f / s;
        float* arow = attn + ((size_t)(b * HH + h) * NN + i) * NN;
        for (int j = l; j < NN; j += 32) arow[j] = sc[h][j] * inv;
    }
}

// ---------------- K6: ctx = attn@v ; out = ctx@W_o + b_o, split x4 ----------
__global__ __launch_bounds__(1024) void k6_out(
    const float* __restrict__ attn, const float* __restrict__ v,
    const float* __restrict__ W_o, const float* __restrict__ b_o,
    float* __restrict__ out) {
    const int b = blockIdx.y, i0 = blockIdx.x * 4;
    const int t = threadIdx.x, d = t & 255, kh = t >> 8;
    __shared__ float ar[4][HH * NN];
    __shared__ float ctx2[DD][5];
    __shared__ float red[4][4][DD];
    for (int idx = t; idx < 4 * HH * NN; idx += 1024) {
        int il = idx / (HH * NN), rem = idx - il * (HH * NN);
        int i = i0 + il; if (i >= NN) i = NN - 1;
        ar[il][rem] = attn[((size_t)b * HH * NN + rem / NN * NN + i) * NN + (rem % NN)];
    }
    __syncthreads();
    {   // phase 1: ctx, j split x4
        int h = d >> 5;
        float acc[4] = {0, 0, 0, 0};
        int j0 = kh * 33, j1 = j0 + 33; if (j1 > NN) j1 = NN;
        for (int j = j0; j < j1; j++) {
            float vv = v[((size_t)b * NN + j) * DD + d];
            int base = h * NN + j;
            acc[0] += ar[0][base] * vv; acc[1] += ar[1][base] * vv;
            acc[2] += ar[2][base] * vv; acc[3] += ar[3][base] * vv;
        }
#pragma unroll
        for (int r = 0; r < 4; r++) red[kh][r][d] = acc[r];
    }
    __syncthreads();
    {   // reduce ctx: thread (r=kh, d)
        float cf = red[0][kh][d] + red[1][kh][d] + red[2][kh][d] + red[3][kh][d];
        ctx2[d][kh] = cf;
    }
    __syncthreads();
    {   // phase 2: out = ctx @ W_o, k split x4
        float o[4] = {0, 0, 0, 0};
        const int kb = kh * 64;
        for (int k = kb; k < kb + 64; k++) {
            float w = W_o[k * DD + d];
            o[0] += ctx2[k][0] * w; o[1] += ctx2[k][1] * w;
            o[2] += ctx2[k][2] * w; o[3] += ctx2[k][3] * w;
        }
#pragma unroll
        for (int r = 0; r < 4; r++) red[kh][r][d] = o[r];
    }
    __syncthreads();
    if (t < 256) {
        float bo = b_o[d];
#pragma unroll
        for (int r = 0; r < 4; r++) {
            int i = i0 + r;
            if (i < NN) {
                float of = red[0][r][d] + red[1][r][d] + red[2][r][d] + red[3][r][d] + bo;
                out[(size_t)(b * NN + i) * DD + d] = of;
            }
        }
    }
}

extern "C" void kernel_launch(void* const* d_in, const int* in_sizes, int n_in,
                              void* d_out, int out_size, void* d_ws, size_t ws_size,
                              hipStream_t stream) {
    const float* desc   = (const float*)d_in[0];
    const float* nv     = (const float*)d_in[1];
    const float* W_gt   = (const float*)d_in[2];
    const float* b_gt   = (const float*)d_in[3];
    // d_in[4] topo_bias unused: sigmoid(x)>0 always, so adjacency sign = sample_sim sign
    const float* W_q    = (const float*)d_in[5];
    const float* b_q    = (const float*)d_in[6];
    const float* W_k    = (const float*)d_in[7];
    const float* b_k    = (const float*)d_in[8];
    const float* W_v    = (const float*)d_in[9];
    const float* b_v    = (const float*)d_in[10];
    const float* W_e1   = (const float*)d_in[11];
    const float* b_e1   = (const float*)d_in[12];
    const float* ln_g   = (const float*)d_in[13];
    const float* ln_b   = (const float*)d_in[14];
    const float* W_e2   = (const float*)d_in[15];
    const float* b_e2   = (const float*)d_in[16];
    const float* w_attn = (const float*)d_in[17];
    const float* b_attn = (const float*)d_in[18];
    const float* W_o    = (const float*)d_in[19];
    const float* b_o    = (const float*)d_in[20];

    float* ws   = (float*)d_ws;
    float* a    = ws + OFF_A;
    float* bp_t = ws + OFF_BPT;
    float* cp_t = ws + OFF_CPT;
    float* vart = ws + OFF_VART;
    float* v    = ws + OFF_V;
    float* sq   = ws + OFF_SQ;
    float* sk   = ws + OFF_SK;
    float* ma   = ws + OFF_MA;
    float* qa   = ws + OFF_QA;
    float* mb   = ws + OFF_MB;
    float* qb   = ws + OFF_QB;
    float* mc   = ws + OFF_MC;
    float* qc   = ws + OFF_QC;
    float* U    = ws + OFF_U;
    float* ub   = ws + OFF_UB;

    float* out  = (float*)d_out;
    float* attn = (float*)d_out + (size_t)BB * NN * DD;

    k0_pre<<<dim3(HH), dim3(256), 0, stream>>>(W_e2, b_e2, w_attn, U, ub);
    k1_rows<<<dim3(SS / 4, BB), dim3(1024), 0, stream>>>(
        desc, nv, W_gt, b_gt, W_e1, b_e1, a, bp_t, cp_t, vart, ma, qa, mb, qb, mc, qc);
    k2_qkv<<<dim3((NN + 3) / 4, BB), dim3(1024), 0, stream>>>(
        nv, W_q, b_q, W_k, b_k, W_v, b_v, w_attn, v, sq, sk);
    k4_mega<<<dim3(NN, BB), dim3(256), 0, stream>>>(
        a, bp_t, cp_t, vart, nv, ma, qa, mb, qb, mc, qc, sq, sk, ln_g, ln_b, U, ub, b_attn, attn);
    k6_out<<<dim3((NN + 3) / 4, BB), dim3(1024), 0, stream>>>(attn, v, W_o, b_o, out);
}

// Round 3
// 197.422 us; speedup vs baseline: 1.3820x; 1.3031x over previous
//
#include <hip/hip_runtime.h>
#include <math.h>

#define BB 8
#define SS 128
#define NN 129
#define DD 256
#define HH 8
#define LN_EPS 1e-5f

// ws layout (float offsets)
#define OFF_A    0        // a:     [B][S][D]
#define OFF_BPT  262144   // bp_t:  [B][D][S]  (b_ + b_e1, transposed)
#define OFF_CPT  524288   // cp_t:  [B][D][S]  (a + b_ + b_e1, transposed)
#define OFF_VART 786432   // var_t: [B][D][S]  (nv[:,1:,:] transposed)
#define OFF_V    1048576  // v:     [B][N][D]
#define OFF_SQ   1312768  // sq:    [B][H][N]
#define OFF_SK   1321024  // sk:    [B][H][N]
#define OFF_MA   1329280
#define OFF_QA   1330304
#define OFF_MB   1331328
#define OFF_QB   1332352
#define OFF_MC   1333376
#define OFF_QC   1334400
#define OFF_U    1335424  // U: [D][H]
#define OFF_UB   1337472  // ubias: [H]

// ---------------- K0: fold W_e2/we -> U, b_e2/we -> ubias -------------------
__global__ void k0_pre(const float* __restrict__ W_e2, const float* __restrict__ b_e2,
                       const float* __restrict__ w_attn, float* __restrict__ U,
                       float* __restrict__ ubias) {
    const int h = blockIdx.x, d = threadIdx.x;
    const float* we = w_attn + 2 * 32;
    float s = 0.f;
#pragma unroll
    for (int q = 0; q < 32; q++) s += W_e2[d * DD + h * 32 + q] * we[q];
    U[d * HH + h] = s;
    if (h == 0 && d < HH) {
        float sb = 0.f;
#pragma unroll
        for (int q = 0; q < 32; q++) sb += b_e2[d * 32 + q] * we[q];
        ubias[d] = sb;
    }
}

// ---------------- K1f: d/a/b projections with float4 weights, split-k x8 ----
__global__ __launch_bounds__(512) void k1f(
    const float* __restrict__ desc, const float* __restrict__ nv,
    const float* __restrict__ W_gt, const float* __restrict__ b_gt,
    const float* __restrict__ W_e1, const float* __restrict__ b_e1,
    float* __restrict__ a, float* __restrict__ bp_t, float* __restrict__ cp_t,
    float* __restrict__ var_t,
    float* __restrict__ ma, float* __restrict__ qa, float* __restrict__ mb,
    float* __restrict__ qb, float* __restrict__ mc, float* __restrict__ qc) {
    const int b = blockIdx.y, s0 = blockIdx.x * 4;
    const int t = threadIdx.x, dq = t & 63, kh = t >> 6;
    __shared__ float dsc[4][DD];
    __shared__ float drow[4][DD];
    __shared__ float4 redA[8][4][64];
    __shared__ float4 redB[8][4][64];
    __shared__ float part[24][4];
    for (int e = t; e < 4 * DD; e += 512)
        dsc[e >> 8][e & 255] = desc[(size_t)(b * SS + s0 + (e >> 8)) * DD + (e & 255)];
    __syncthreads();
    {   // phase A: d = desc @ W_gt (partial over 32 k)
        float4 acc[4];
#pragma unroll
        for (int r = 0; r < 4; r++) acc[r] = make_float4(0.f, 0.f, 0.f, 0.f);
        const int kb = kh * 32;
#pragma unroll 4
        for (int k = kb; k < kb + 32; k++) {
            float4 w = *(const float4*)&W_gt[k * DD + 4 * dq];
#pragma unroll
            for (int r = 0; r < 4; r++) {
                float x = dsc[r][k];
                acc[r].x = fmaf(x, w.x, acc[r].x);
                acc[r].y = fmaf(x, w.y, acc[r].y);
                acc[r].z = fmaf(x, w.z, acc[r].z);
                acc[r].w = fmaf(x, w.w, acc[r].w);
            }
        }
#pragma unroll
        for (int r = 0; r < 4; r++) redA[kh][r][dq] = acc[r];
    }
    __syncthreads();
    for (int e = t; e < 4 * DD; e += 512) {
        int r = e >> 8, d2 = e & 255;
        float s = b_gt[d2];
#pragma unroll
        for (int kk = 0; kk < 8; kk++) s += ((const float*)redA[kk][r])[d2];
        drow[r][d2] = s;
    }
    __syncthreads();
    {   // phase B: a = d @ We1_top ; b = d @ We1_bot
        float4 aa[4], ab[4];
#pragma unroll
        for (int r = 0; r < 4; r++) { aa[r] = make_float4(0.f, 0.f, 0.f, 0.f); ab[r] = aa[r]; }
        const int kb = kh * 32;
#pragma unroll 2
        for (int k = kb; k < kb + 32; k++) {
            float4 wa = *(const float4*)&W_e1[k * DD + 4 * dq];
            float4 wb = *(const float4*)&W_e1[(DD + k) * DD + 4 * dq];
#pragma unroll
            for (int r = 0; r < 4; r++) {
                float x = drow[r][k];
                aa[r].x = fmaf(x, wa.x, aa[r].x); aa[r].y = fmaf(x, wa.y, aa[r].y);
                aa[r].z = fmaf(x, wa.z, aa[r].z); aa[r].w = fmaf(x, wa.w, aa[r].w);
                ab[r].x = fmaf(x, wb.x, ab[r].x); ab[r].y = fmaf(x, wb.y, ab[r].y);
                ab[r].z = fmaf(x, wb.z, ab[r].z); ab[r].w = fmaf(x, wb.w, ab[r].w);
            }
        }
#pragma unroll
        for (int r = 0; r < 4; r++) { redA[kh][r][dq] = aa[r]; redB[kh][r][dq] = ab[r]; }
    }
    __syncthreads();
    if (t < 256) {
        const int d2 = t;
        float avf[4], bvf[4], cvf[4];
        float be1 = b_e1[d2];
#pragma unroll
        for (int r = 0; r < 4; r++) {
            float sa = 0.f, sb = 0.f;
#pragma unroll
            for (int kk = 0; kk < 8; kk++) {
                sa += ((const float*)redA[kk][r])[d2];
                sb += ((const float*)redB[kk][r])[d2];
            }
            avf[r] = sa; bvf[r] = sb + be1; cvf[r] = avf[r] + bvf[r];
        }
#pragma unroll
        for (int r = 0; r < 4; r++) a[(size_t)(b * SS + s0 + r) * DD + d2] = avf[r];
        float4 f4;
        f4.x = bvf[0]; f4.y = bvf[1]; f4.z = bvf[2]; f4.w = bvf[3];
        *(float4*)(bp_t + (size_t)(b * DD + d2) * SS + s0) = f4;
        f4.x = cvf[0]; f4.y = cvf[1]; f4.z = cvf[2]; f4.w = cvf[3];
        *(float4*)(cp_t + (size_t)(b * DD + d2) * SS + s0) = f4;
        float nvv[4];
#pragma unroll
        for (int r = 0; r < 4; r++) nvv[r] = nv[(size_t)(b * NN + 1 + s0 + r) * DD + d2];
        f4.x = nvv[0]; f4.y = nvv[1]; f4.z = nvv[2]; f4.w = nvv[3];
        *(float4*)(var_t + (size_t)(b * DD + d2) * SS + s0) = f4;
        float vals[24];
#pragma unroll
        for (int r = 0; r < 4; r++) {
            vals[r * 6 + 0] = avf[r]; vals[r * 6 + 1] = avf[r] * avf[r];
            vals[r * 6 + 2] = bvf[r]; vals[r * 6 + 3] = bvf[r] * bvf[r];
            vals[r * 6 + 4] = cvf[r]; vals[r * 6 + 5] = cvf[r] * cvf[r];
        }
        int lane = t & 63, wid = t >> 6;
#pragma unroll
        for (int vv = 0; vv < 24; vv++) {
            float x = vals[vv];
            for (int o = 32; o; o >>= 1) x += __shfl_xor(x, o, 64);
            if (lane == 0) part[vv][wid] = x;
        }
    }
    __syncthreads();
    if (t < 24) {
        float ssum = (part[t][0] + part[t][1]) + (part[t][2] + part[t][3]);
        int st = t % 6;
        int row = b * SS + s0 + t / 6;
        float m = ssum * (1.f / DD);
        float* dstp = (st == 0) ? ma : (st == 1) ? qa : (st == 2) ? mb
                     : (st == 3) ? qb : (st == 4) ? mc : qc;
        dstp[row] = m;
    }
}

// ---------------- K2f: qkv with float4 weights, split-k x4 ------------------
__global__ __launch_bounds__(256) void k2f(
    const float* __restrict__ nv,
    const float* __restrict__ W_q, const float* __restrict__ b_q,
    const float* __restrict__ W_k, const float* __restrict__ b_k,
    const float* __restrict__ W_v, const float* __restrict__ b_v,
    const float* __restrict__ w_attn,
    float* __restrict__ v, float* __restrict__ sq, float* __restrict__ sk) {
    const int b = blockIdx.y, n0 = blockIdx.x * 4;
    const int t = threadIdx.x, dq = t & 63, kh = t >> 6;
    __shared__ float rows[4][DD];
    __shared__ float4 redq[4][4][64];
    __shared__ float4 redk[4][4][64];
    __shared__ float4 redv[4][4][64];
    for (int e = t; e < 4 * DD; e += 256) {
        int r = e >> 8, d2 = e & 255;
        int n = n0 + r; if (n >= NN) n = NN - 1;
        rows[r][d2] = nv[(size_t)(b * NN + n) * DD + d2];
    }
    __syncthreads();
    {
        float4 aq[4], ak[4], av[4];
#pragma unroll
        for (int r = 0; r < 4; r++) {
            aq[r] = make_float4(0.f, 0.f, 0.f, 0.f); ak[r] = aq[r]; av[r] = aq[r];
        }
        const int kb = kh * 64;
#pragma unroll 2
        for (int k = kb; k < kb + 64; k++) {
            float4 wq = *(const float4*)&W_q[k * DD + 4 * dq];
            float4 wk = *(const float4*)&W_k[k * DD + 4 * dq];
            float4 wv = *(const float4*)&W_v[k * DD + 4 * dq];
#pragma unroll
            for (int r = 0; r < 4; r++) {
                float x = rows[r][k];
                aq[r].x = fmaf(x, wq.x, aq[r].x); aq[r].y = fmaf(x, wq.y, aq[r].y);
                aq[r].z = fmaf(x, wq.z, aq[r].z); aq[r].w = fmaf(x, wq.w, aq[r].w);
                ak[r].x = fmaf(x, wk.x, ak[r].x); ak[r].y = fmaf(x, wk.y, ak[r].y);
                ak[r].z = fmaf(x, wk.z, ak[r].z); ak[r].w = fmaf(x, wk.w, ak[r].w);
                av[r].x = fmaf(x, wv.x, av[r].x); av[r].y = fmaf(x, wv.y, av[r].y);
                av[r].z = fmaf(x, wv.z, av[r].z); av[r].w = fmaf(x, wv.w, av[r].w);
            }
        }
#pragma unroll
        for (int r = 0; r < 4; r++) { redq[kh][r][dq] = aq[r]; redk[kh][r][dq] = ak[r]; redv[kh][r][dq] = av[r]; }
    }
    __syncthreads();
    {
        const int d2 = t;
        float bq = b_q[d2], bk = b_k[d2], bvb = b_v[d2];
        float waq = w_attn[d2 & 31];
        float wak = w_attn[32 + (d2 & 31)];
        int h = d2 >> 5;
#pragma unroll
        for (int r = 0; r < 4; r++) {
            float qf = bq, kf = bk, vf = bvb;
#pragma unroll
            for (int kk = 0; kk < 4; kk++) {
                qf += ((const float*)redq[kk][r])[d2];
                kf += ((const float*)redk[kk][r])[d2];
                vf += ((const float*)redv[kk][r])[d2];
            }
            int n = n0 + r;
            if (n < NN) v[(size_t)(b * NN + n) * DD + d2] = vf;
            float xq = qf * waq, xk = kf * wak;
#pragma unroll
            for (int o = 16; o; o >>= 1) { xq += __shfl_xor(xq, o, 64); xk += __shfl_xor(xk, o, 64); }
            if ((d2 & 31) == 0 && n < NN) { sq[(b * HH + h) * NN + n] = xq; sk[(b * HH + h) * NN + n] = xk; }
        }
    }
}

// ---------------- K4f: adjacency+LN+relu+U-dot+scores+softmax+ctx+out -------
__global__ __launch_bounds__(256) void k4f(
    const float* __restrict__ a, const float* __restrict__ bp_t, const float* __restrict__ cp_t,
    const float* __restrict__ var_t, const float* __restrict__ nv,
    const float* __restrict__ vbuf,
    const float* __restrict__ ma, const float* __restrict__ qa,
    const float* __restrict__ mb, const float* __restrict__ qb,
    const float* __restrict__ mc, const float* __restrict__ qc,
    const float* __restrict__ sq, const float* __restrict__ sk,
    const float* __restrict__ ln_g, const float* __restrict__ ln_b,
    const float* __restrict__ U, const float* __restrict__ ubias,
    const float* __restrict__ b_attn,
    const float* __restrict__ W_o, const float* __restrict__ b_o,
    float* __restrict__ attn, float* __restrict__ out) {
    const int b = blockIdx.x, tile = blockIdx.y;
    const int i0 = tile * 4;
    const int ILV = (tile == 32) ? 1 : 4;
    const int t = threadIdx.x;
    const int wv = t >> 6, dh = (t >> 5) & 1, jq = t & 31;
    const int il = wv;
    const int i = i0 + il;
    const bool ok = (il < ILV);

    __shared__ float Arow[4][DD];
    __shared__ float Vrow[4][DD];
    __shared__ __attribute__((aligned(16))) float Usm[DD][HH];
    __shared__ float2 lnsm[DD];
    __shared__ float sksm[HH * NN];
    __shared__ float ubsm[HH];
    __shared__ float4 redpc[4][2][32];
    __shared__ float4 redpv[4][2][32];
    __shared__ float accred[4][32][33];
    __shared__ float sc[4][HH][132];
    __shared__ float csm[4][DD];

    // ---- stage ----
    for (int e = t; e < 4 * DD; e += 256) {
        int il2 = e >> 8, d2 = e & 255;
        int i2 = i0 + il2;
        Arow[il2][d2] = (i2 >= 1 && i2 < NN) ? a[(size_t)(b * SS + i2 - 1) * DD + d2] : 0.f;
        int ic = i2 < NN ? i2 : NN - 1;
        Vrow[il2][d2] = nv[(size_t)(b * NN + ic) * DD + d2];
    }
    for (int e = t; e < DD * HH; e += 256) ((float*)Usm)[e] = U[e];
    { float2 g; g.x = ln_g[t]; g.y = ln_b[t]; lnsm[t] = g; }
    for (int e = t; e < HH * NN; e += 256) sksm[e] = sk[b * (HH * NN) + e];
    if (t < HH) ubsm[t] = ubias[t];
    __syncthreads();

    // ---- pass 1: cross = a_i . b'_j ; dvv = nv_i . nv_j ----
    {
        float4 cr = make_float4(0.f, 0.f, 0.f, 0.f), dv = cr;
        if (ok && i >= 1) {
            const int d0 = dh * 128;
            const float* bc = bp_t + ((size_t)b * DD + d0) * SS + 4 * jq;
            const float* vc = var_t + ((size_t)b * DD + d0) * SS + 4 * jq;
#pragma unroll 4
            for (int dd = 0; dd < 128; dd++) {
                float4 b4 = *(const float4*)(bc + (size_t)dd * SS);
                float4 v4 = *(const float4*)(vc + (size_t)dd * SS);
                float A = Arow[il][d0 + dd];
                float V = Vrow[il][d0 + dd];
                cr.x = fmaf(A, b4.x, cr.x); cr.y = fmaf(A, b4.y, cr.y);
                cr.z = fmaf(A, b4.z, cr.z); cr.w = fmaf(A, b4.w, cr.w);
                dv.x = fmaf(V, v4.x, dv.x); dv.y = fmaf(V, v4.y, dv.y);
                dv.z = fmaf(V, v4.z, dv.z); dv.w = fmaf(V, v4.w, dv.w);
            }
        }
        redpc[wv][dh][jq] = cr;
        redpv[wv][dh][jq] = dv;
    }
    __syncthreads();
    float rs[4], nm[4], mkv[4];
    if (ok) {
        float4 c0 = redpc[wv][0][jq], c1 = redpc[wv][1][jq];
        float4 v0 = redpv[wv][0][jq], v1 = redpv[wv][1][jq];
        float crj[4] = {c0.x + c1.x, c0.y + c1.y, c0.z + c1.z, c0.w + c1.w};
        float dvj[4] = {v0.x + v1.x, v0.y + v1.y, v0.z + v1.z, v0.w + v1.w};
#pragma unroll
        for (int jj = 0; jj < 4; jj++) {
            int j = 4 * jq + jj;
            float mu, var, mk;
            if (i == 0) {
                float muC = mc[b * SS + j], qC = qc[b * SS + j];
                mu = muC; var = qC - muC * muC; mk = 1.f;
            } else {
                float muA = ma[b * SS + i - 1], qA = qa[b * SS + i - 1];
                float muB = mb[b * SS + j], qB = qb[b * SS + j];
                mu = muA + muB;
                var = qA + qB + 2.f * crj[jj] * (1.f / DD) - mu * mu;
                mk = ((i - 1) != j && dvj[jj] > 0.f) ? 1.f : 0.f;
            }
            float r = rsqrtf(var + LN_EPS);
            rs[jj] = r; nm[jj] = -mu * r; mkv[jj] = mk;
        }
    }

    // ---- pass 2: LN + relu + U-dot ----
    float acc[4][HH];
#pragma unroll
    for (int jj = 0; jj < 4; jj++)
#pragma unroll
        for (int h = 0; h < HH; h++) acc[jj][h] = 0.f;
    if (ok) {
        const float* Bsrc = ((i == 0) ? cp_t : bp_t) + (size_t)b * DD * SS + 4 * jq;
        const int d0 = dh * 128;
#pragma unroll 2
        for (int dd = 0; dd < 128; dd++) {
            const int d2 = d0 + dd;
            float4 b4 = *(const float4*)(Bsrc + (size_t)d2 * SS);
            float A = Arow[il][d2];
            float2 gb = lnsm[d2];
            float4 u0 = *(const float4*)&Usm[d2][0];
            float4 u1 = *(const float4*)&Usm[d2][4];
            float bj[4] = {b4.x, b4.y, b4.z, b4.w};
#pragma unroll
            for (int jj = 0; jj < 4; jj++) {
                float pre = A + bj[jj];
                float y = fmaf(pre, rs[jj], nm[jj]);
                y = fmaf(y, gb.x, gb.y);
                float rr = fmaxf(y, 0.f);
                acc[jj][0] = fmaf(rr, u0.x, acc[jj][0]);
                acc[jj][1] = fmaf(rr, u0.y, acc[jj][1]);
                acc[jj][2] = fmaf(rr, u0.z, acc[jj][2]);
                acc[jj][3] = fmaf(rr, u0.w, acc[jj][3]);
                acc[jj][4] = fmaf(rr, u1.x, acc[jj][4]);
                acc[jj][5] = fmaf(rr, u1.y, acc[jj][5]);
                acc[jj][6] = fmaf(rr, u1.z, acc[jj][6]);
                acc[jj][7] = fmaf(rr, u1.w, acc[jj][7]);
            }
        }
    }
    if (dh == 1) {
#pragma unroll
        for (int jj = 0; jj < 4; jj++)
#pragma unroll
            for (int h = 0; h < HH; h++) accred[wv][jq][jj * 8 + h] = acc[jj][h];
    }
    __syncthreads();
    if (ok && dh == 0) {
        const float ba = b_attn[0];
#pragma unroll
        for (int jj = 0; jj < 4; jj++)
#pragma unroll
            for (int h = 0; h < HH; h++) acc[jj][h] += accred[wv][jq][jj * 8 + h];
#pragma unroll
        for (int h = 0; h < HH; h++) {
            float sqv = sq[b * (HH * NN) + h * NN + i];
#pragma unroll
            for (int jj = 0; jj < 4; jj++) {
                int j = 4 * jq + jj;
                float pen = (mkv[jj] == 0.f) ? -1e9f : 0.f;
                float ew = (acc[jj][h] + ubsm[h]) * mkv[jj];
                sc[il][h][1 + j] = sqv + sksm[h * NN + 1 + j] + ew + ba + pen;
            }
            if (jq == 0) sc[il][h][0] = sqv + sksm[h * NN] + ba - 1e9f;
        }
    }
    __syncthreads();

    // ---- softmax (8 lanes per (il,h) row) ----
    {
        int row = t >> 3, l = t & 7;
        int il2 = row >> 3, h2 = row & 7;
        if (il2 < ILV) {
            float m = -INFINITY;
            for (int j = l; j < NN; j += 8) m = fmaxf(m, sc[il2][h2][j]);
#pragma unroll
            for (int o = 4; o; o >>= 1) m = fmaxf(m, __shfl_xor(m, o, 64));
            float s = 0.f;
            for (int j = l; j < NN; j += 8) { float ex = __expf(sc[il2][h2][j] - m); sc[il2][h2][j] = ex; s += ex; }
#pragma unroll
            for (int o = 4; o; o >>= 1) s += __shfl_xor(s, o, 64);
            float inv = 1.f / s;
            for (int j = l; j < NN; j += 8) sc[il2][h2][j] *= inv;
        }
    }
    __syncthreads();

    // ---- write attn (coalesced-ish) ----
    for (int e = t; e < ILV * 1056; e += 256) {
        int il2 = e / 1056, r2 = e - il2 * 1056;
        int h2 = r2 / 132, j2 = r2 - h2 * 132;
        if (j2 < NN)
            attn[((size_t)(b * HH + h2) * NN + (i0 + il2)) * NN + j2] = sc[il2][h2][j2];
    }

    // ---- ctx = p @ v ----
    {
        const int d2 = t;
        const int hd2 = d2 >> 5;
        float cacc[4] = {0.f, 0.f, 0.f, 0.f};
        for (int j = 0; j < NN; j++) {
            float vv = vbuf[((size_t)b * NN + j) * DD + d2];
            cacc[0] = fmaf(sc[0][hd2][j], vv, cacc[0]);
            cacc[1] = fmaf(sc[1][hd2][j], vv, cacc[1]);
            cacc[2] = fmaf(sc[2][hd2][j], vv, cacc[2]);
            cacc[3] = fmaf(sc[3][hd2][j], vv, cacc[3]);
        }
        for (int il2 = 0; il2 < ILV; il2++) csm[il2][d2] = cacc[il2];
    }
    __syncthreads();

    // ---- out = ctx @ W_o + b_o (split-k x4 over waves) ----
    {
        float4* outred = (float4*)accred;
        const int dq2 = t & 63, kh2 = t >> 6;
        float4 oacc[4];
#pragma unroll
        for (int il2 = 0; il2 < 4; il2++) oacc[il2] = make_float4(0.f, 0.f, 0.f, 0.f);
        const int kb = kh2 * 64;
#pragma unroll 2
        for (int k = kb; k < kb + 64; k++) {
            float4 w = *(const float4*)&W_o[k * DD + 4 * dq2];
#pragma unroll
            for (int il2 = 0; il2 < 4; il2++) {
                float x = csm[il2][k];
                oacc[il2].x = fmaf(x, w.x, oacc[il2].x);
                oacc[il2].y = fmaf(x, w.y, oacc[il2].y);
                oacc[il2].z = fmaf(x, w.z, oacc[il2].z);
                oacc[il2].w = fmaf(x, w.w, oacc[il2].w);
            }
        }
        __syncthreads();  // accred (alias) free for reuse
#pragma unroll
        for (int il2 = 0; il2 < 4; il2++) outred[(kh2 * 4 + il2) * 64 + dq2] = oacc[il2];
    }
    __syncthreads();
    {
        const int d2 = t;
        const float* orf = (const float*)accred;
        float bo = b_o[d2];
        for (int il2 = 0; il2 < ILV; il2++) {
            float s = bo;
#pragma unroll
            for (int kk = 0; kk < 4; kk++) s += orf[(kk * 4 + il2) * 256 + d2];
            out[((size_t)b * NN + i0 + il2) * DD + d2] = s;
        }
    }
}

extern "C" void kernel_launch(void* const* d_in, const int* in_sizes, int n_in,
                              void* d_out, int out_size, void* d_ws, size_t ws_size,
                              hipStream_t stream) {
    const float* desc   = (const float*)d_in[0];
    const float* nv     = (const float*)d_in[1];
    const float* W_gt   = (const float*)d_in[2];
    const float* b_gt   = (const float*)d_in[3];
    // d_in[4] topo_bias unused: sigmoid(x)>0 always, so adjacency sign = sample_sim sign
    const float* W_q    = (const float*)d_in[5];
    const float* b_q    = (const float*)d_in[6];
    const float* W_k    = (const float*)d_in[7];
    const float* b_k    = (const float*)d_in[8];
    const float* W_v    = (const float*)d_in[9];
    const float* b_v    = (const float*)d_in[10];
    const float* W_e1   = (const float*)d_in[11];
    const float* b_e1   = (const float*)d_in[12];
    const float* ln_g   = (const float*)d_in[13];
    const float* ln_b   = (const float*)d_in[14];
    const float* W_e2   = (const float*)d_in[15];
    const float* b_e2   = (const float*)d_in[16];
    const float* w_attn = (const float*)d_in[17];
    const float* b_attn = (const float*)d_in[18];
    const float* W_o    = (const float*)d_in[19];
    const float* b_o    = (const float*)d_in[20];

    float* ws   = (float*)d_ws;
    float* a    = ws + OFF_A;
    float* bp_t = ws + OFF_BPT;
    float* cp_t = ws + OFF_CPT;
    float* vart = ws + OFF_VART;
    float* v    = ws + OFF_V;
    float* sq   = ws + OFF_SQ;
    float* sk   = ws + OFF_SK;
    float* ma   = ws + OFF_MA;
    float* qa   = ws + OFF_QA;
    float* mb   = ws + OFF_MB;
    float* qb   = ws + OFF_QB;
    float* mc   = ws + OFF_MC;
    float* qc   = ws + OFF_QC;
    float* U    = ws + OFF_U;
    float* ub   = ws + OFF_UB;

    float* out  = (float*)d_out;
    float* attn = (float*)d_out + (size_t)BB * NN * DD;

    k0_pre<<<dim3(HH), dim3(256), 0, stream>>>(W_e2, b_e2, w_attn, U, ub);
    k1f<<<dim3(SS / 4, BB), dim3(512), 0, stream>>>(
        desc, nv, W_gt, b_gt, W_e1, b_e1, a, bp_t, cp_t, vart, ma, qa, mb, qb, mc, qc);
    k2f<<<dim3((NN + 3) / 4, BB), dim3(256), 0, stream>>>(
        nv, W_q, b_q, W_k, b_k, W_v, b_v, w_attn, v, sq, sk);
    k4f<<<dim3(BB, 33), dim3(256), 0, stream>>>(
        a, bp_t, cp_t, vart, nv, v, ma, qa, mb, qb, mc, qc, sq, sk,
        ln_g, ln_b, U, ub, b_attn, W_o, b_o, attn, out);
}

// Round 4
// 189.814 us; speedup vs baseline: 1.4374x; 1.0401x over previous
//
#include <hip/hip_runtime.h>
#include <math.h>

#define BB 8
#define SS 128
#define NN 129
#define DD 256
#define HH 8
#define LN_EPS 1e-5f

// ws layout (float offsets)
#define OFF_A    0        // a:     [B][S][D]
#define OFF_BPT  262144   // bp_t:  [B][D][S]  (b_ + b_e1, transposed)
#define OFF_CPT  524288   // cp_t:  [B][D][S]  (a + b_ + b_e1, transposed)
#define OFF_VART 786432   // var_t: [B][D][S]  (nv[:,1:,:] transposed)
#define OFF_V    1048576  // v:     [B][N][D]
#define OFF_SQ   1312768  // sq:    [B][H][N]
#define OFF_SK   1321024  // sk:    [B][H][N]
#define OFF_MA   1329280
#define OFF_QA   1330304
#define OFF_MB   1331328
#define OFF_QB   1332352
#define OFF_MC   1333376
#define OFF_QC   1334400
#define OFF_U    1335424  // U: [D][H]
#define OFF_UB   1337472  // ubias: [H]

struct SA {  // part A: k1 work (~40.4 KB)
    float dsc[4][DD];
    float drow[4][DD];
    float4 red[8][4][64];
    float part[24][4];
};
struct SB {  // part B: k2 work (~34 KB)
    float rows[2][DD];
    float4 redq[8][2][64];
    float4 redk[8][2][64];
};
union SMA { SA a; SB b; };

// ============ KA: projections + stats + transposes + U-fold =================
__global__ __launch_bounds__(512) void ka_all(
    const float* __restrict__ desc, const float* __restrict__ nv,
    const float* __restrict__ W_gt, const float* __restrict__ b_gt,
    const float* __restrict__ W_e1, const float* __restrict__ b_e1,
    const float* __restrict__ W_q, const float* __restrict__ b_q,
    const float* __restrict__ W_k, const float* __restrict__ b_k,
    const float* __restrict__ W_v, const float* __restrict__ b_v,
    const float* __restrict__ W_e2, const float* __restrict__ b_e2,
    const float* __restrict__ w_attn,
    float* __restrict__ a, float* __restrict__ bp_t, float* __restrict__ cp_t,
    float* __restrict__ var_t, float* __restrict__ v,
    float* __restrict__ sq, float* __restrict__ sk,
    float* __restrict__ ma, float* __restrict__ qa, float* __restrict__ mb,
    float* __restrict__ qb, float* __restrict__ mc, float* __restrict__ qc,
    float* __restrict__ U, float* __restrict__ ubias) {
    __shared__ SMA sm;
    const int bx = blockIdx.x, t = threadIdx.x;

    if (bx < 256) {
        // ---------------- part A: d = desc@W_gt; a = d@We1_t; b = d@We1_b ----
        SA& S = sm.a;
        const int b = bx >> 5, s0 = (bx & 31) * 4;
        const int dq = t & 63, kh = t >> 6;
        for (int e = t; e < 4 * DD; e += 512)
            S.dsc[e >> 8][e & 255] = desc[(size_t)(b * SS + s0 + (e >> 8)) * DD + (e & 255)];
        __syncthreads();
        {   // d-gemm, split-k x8
            float4 acc[4];
#pragma unroll
            for (int r = 0; r < 4; r++) acc[r] = make_float4(0.f, 0.f, 0.f, 0.f);
            const int kb = kh * 32;
#pragma unroll 4
            for (int k = kb; k < kb + 32; k++) {
                float4 w = *(const float4*)&W_gt[k * DD + 4 * dq];
#pragma unroll
                for (int r = 0; r < 4; r++) {
                    float x = S.dsc[r][k];
                    acc[r].x = fmaf(x, w.x, acc[r].x); acc[r].y = fmaf(x, w.y, acc[r].y);
                    acc[r].z = fmaf(x, w.z, acc[r].z); acc[r].w = fmaf(x, w.w, acc[r].w);
                }
            }
#pragma unroll
            for (int r = 0; r < 4; r++) S.red[kh][r][dq] = acc[r];
        }
        __syncthreads();
        for (int e = t; e < 4 * DD; e += 512) {
            int r = e >> 8, d2 = e & 255;
            float s = b_gt[d2];
#pragma unroll
            for (int kk = 0; kk < 8; kk++) s += ((const float*)S.red[kk][r])[d2];
            S.drow[r][d2] = s;
        }
        __syncthreads();
        {   // a-gemm
            float4 acc[4];
#pragma unroll
            for (int r = 0; r < 4; r++) acc[r] = make_float4(0.f, 0.f, 0.f, 0.f);
            const int kb = kh * 32;
#pragma unroll 4
            for (int k = kb; k < kb + 32; k++) {
                float4 w = *(const float4*)&W_e1[k * DD + 4 * dq];
#pragma unroll
                for (int r = 0; r < 4; r++) {
                    float x = S.drow[r][k];
                    acc[r].x = fmaf(x, w.x, acc[r].x); acc[r].y = fmaf(x, w.y, acc[r].y);
                    acc[r].z = fmaf(x, w.z, acc[r].z); acc[r].w = fmaf(x, w.w, acc[r].w);
                }
            }
#pragma unroll
            for (int r = 0; r < 4; r++) S.red[kh][r][dq] = acc[r];
        }
        __syncthreads();
        float avf[4];
        if (t < 256) {
            const int d2 = t;
#pragma unroll
            for (int r = 0; r < 4; r++) {
                float s = 0.f;
#pragma unroll
                for (int kk = 0; kk < 8; kk++) s += ((const float*)S.red[kk][r])[d2];
                avf[r] = s;
                a[(size_t)(b * SS + s0 + r) * DD + d2] = s;
            }
        }
        __syncthreads();
        {   // b-gemm
            float4 acc[4];
#pragma unroll
            for (int r = 0; r < 4; r++) acc[r] = make_float4(0.f, 0.f, 0.f, 0.f);
            const int kb = kh * 32;
#pragma unroll 4
            for (int k = kb; k < kb + 32; k++) {
                float4 w = *(const float4*)&W_e1[(DD + k) * DD + 4 * dq];
#pragma unroll
                for (int r = 0; r < 4; r++) {
                    float x = S.drow[r][k];
                    acc[r].x = fmaf(x, w.x, acc[r].x); acc[r].y = fmaf(x, w.y, acc[r].y);
                    acc[r].z = fmaf(x, w.z, acc[r].z); acc[r].w = fmaf(x, w.w, acc[r].w);
                }
            }
#pragma unroll
            for (int r = 0; r < 4; r++) S.red[kh][r][dq] = acc[r];
        }
        __syncthreads();
        if (t < 256) {
            const int d2 = t;
            float bvf[4], cvf[4];
            float be1 = b_e1[d2];
#pragma unroll
            for (int r = 0; r < 4; r++) {
                float s = 0.f;
#pragma unroll
                for (int kk = 0; kk < 8; kk++) s += ((const float*)S.red[kk][r])[d2];
                bvf[r] = s + be1; cvf[r] = avf[r] + bvf[r];
            }
            float4 f4;
            f4.x = bvf[0]; f4.y = bvf[1]; f4.z = bvf[2]; f4.w = bvf[3];
            *(float4*)(bp_t + (size_t)(b * DD + d2) * SS + s0) = f4;
            f4.x = cvf[0]; f4.y = cvf[1]; f4.z = cvf[2]; f4.w = cvf[3];
            *(float4*)(cp_t + (size_t)(b * DD + d2) * SS + s0) = f4;
            float nvv[4];
#pragma unroll
            for (int r = 0; r < 4; r++) nvv[r] = nv[(size_t)(b * NN + 1 + s0 + r) * DD + d2];
            f4.x = nvv[0]; f4.y = nvv[1]; f4.z = nvv[2]; f4.w = nvv[3];
            *(float4*)(var_t + (size_t)(b * DD + d2) * SS + s0) = f4;
            float vals[24];
#pragma unroll
            for (int r = 0; r < 4; r++) {
                vals[r * 6 + 0] = avf[r]; vals[r * 6 + 1] = avf[r] * avf[r];
                vals[r * 6 + 2] = bvf[r]; vals[r * 6 + 3] = bvf[r] * bvf[r];
                vals[r * 6 + 4] = cvf[r]; vals[r * 6 + 5] = cvf[r] * cvf[r];
            }
            int lane = t & 63, wid = t >> 6;
#pragma unroll
            for (int vv = 0; vv < 24; vv++) {
                float x = vals[vv];
                for (int o = 32; o; o >>= 1) x += __shfl_xor(x, o, 64);
                if (lane == 0) S.part[vv][wid] = x;
            }
        }
        __syncthreads();
        if (t < 24) {
            float ssum = (S.part[t][0] + S.part[t][1]) + (S.part[t][2] + S.part[t][3]);
            int st = t % 6;
            int row = b * SS + s0 + t / 6;
            float m = ssum * (1.f / DD);
            float* dstp = (st == 0) ? ma : (st == 1) ? qa : (st == 2) ? mb
                         : (st == 3) ? qb : (st == 4) ? mc : qc;
            dstp[row] = m;
        }
    } else if (bx < 776) {
        // ---------------- part B: qkv on 2 rows, split-k x8 ------------------
        SB& S = sm.b;
        const int idx = bx - 256;
        const int b = idx / 65, n0 = (idx % 65) * 2;
        const int dq = t & 63, kh = t >> 6;
        if (t < 512) {
            int r = t >> 8, d2 = t & 255;
            int n = n0 + r; if (n >= NN) n = NN - 1;
            S.rows[r][d2] = nv[(size_t)(b * NN + n) * DD + d2];
        }
        __syncthreads();
        {   // Q,K sweep
            float4 aq[2], ak[2];
#pragma unroll
            for (int r = 0; r < 2; r++) { aq[r] = make_float4(0.f, 0.f, 0.f, 0.f); ak[r] = aq[r]; }
            const int kb = kh * 32;
#pragma unroll 4
            for (int k = kb; k < kb + 32; k++) {
                float4 wq = *(const float4*)&W_q[k * DD + 4 * dq];
                float4 wk = *(const float4*)&W_k[k * DD + 4 * dq];
#pragma unroll
                for (int r = 0; r < 2; r++) {
                    float x = S.rows[r][k];
                    aq[r].x = fmaf(x, wq.x, aq[r].x); aq[r].y = fmaf(x, wq.y, aq[r].y);
                    aq[r].z = fmaf(x, wq.z, aq[r].z); aq[r].w = fmaf(x, wq.w, aq[r].w);
                    ak[r].x = fmaf(x, wk.x, ak[r].x); ak[r].y = fmaf(x, wk.y, ak[r].y);
                    ak[r].z = fmaf(x, wk.z, ak[r].z); ak[r].w = fmaf(x, wk.w, ak[r].w);
                }
            }
#pragma unroll
            for (int r = 0; r < 2; r++) { S.redq[kh][r][dq] = aq[r]; S.redk[kh][r][dq] = ak[r]; }
        }
        __syncthreads();
        {   // finalize q,k -> sq,sk
            const int d2 = t & 255, r = t >> 8;
            const int n = n0 + r;
            float qf = b_q[d2], kf = b_k[d2];
#pragma unroll
            for (int kk = 0; kk < 8; kk++) {
                qf += ((const float*)S.redq[kk][r])[d2];
                kf += ((const float*)S.redk[kk][r])[d2];
            }
            float xq = qf * w_attn[d2 & 31];
            float xk = kf * w_attn[32 + (d2 & 31)];
#pragma unroll
            for (int o = 16; o; o >>= 1) { xq += __shfl_xor(xq, o, 32); xk += __shfl_xor(xk, o, 32); }
            if ((d2 & 31) == 0 && n < NN) {
                sq[(size_t)(b * HH + (d2 >> 5)) * NN + n] = xq;
                sk[(size_t)(b * HH + (d2 >> 5)) * NN + n] = xk;
            }
        }
        __syncthreads();
        {   // V sweep (reuse redq)
            float4 av[2];
#pragma unroll
            for (int r = 0; r < 2; r++) av[r] = make_float4(0.f, 0.f, 0.f, 0.f);
            const int kb = kh * 32;
#pragma unroll 4
            for (int k = kb; k < kb + 32; k++) {
                float4 wv = *(const float4*)&W_v[k * DD + 4 * dq];
#pragma unroll
                for (int r = 0; r < 2; r++) {
                    float x = S.rows[r][k];
                    av[r].x = fmaf(x, wv.x, av[r].x); av[r].y = fmaf(x, wv.y, av[r].y);
                    av[r].z = fmaf(x, wv.z, av[r].z); av[r].w = fmaf(x, wv.w, av[r].w);
                }
            }
#pragma unroll
            for (int r = 0; r < 2; r++) S.redq[kh][r][dq] = av[r];
        }
        __syncthreads();
        {
            const int d2 = t & 255, r = t >> 8;
            const int n = n0 + r;
            if (n < NN) {
                float vf = b_v[d2];
#pragma unroll
                for (int kk = 0; kk < 8; kk++) vf += ((const float*)S.redq[kk][r])[d2];
                v[(size_t)(b * NN + n) * DD + d2] = vf;
            }
        }
    } else {
        // ---------------- part C: fold W_e2/we -> U (coalesced) --------------
        const int ri = bx - 776;  // 0..63, rows ri*4..ri*4+3
        if (t < 256) {
            const int c = t;
            const float wec = w_attn[64 + (c & 31)];
#pragma unroll
            for (int rr = 0; rr < 4; rr++) {
                int r = ri * 4 + rr;
                float x = W_e2[(size_t)r * DD + c] * wec;
#pragma unroll
                for (int o = 16; o; o >>= 1) x += __shfl_xor(x, o, 32);
                if ((c & 31) == 0) U[r * HH + (c >> 5)] = x;
            }
            if (ri == 0) {
                float x = b_e2[c] * wec;
#pragma unroll
                for (int o = 16; o; o >>= 1) x += __shfl_xor(x, o, 32);
                if ((c & 31) == 0) ubias[c >> 5] = x;
            }
        }
    }
}

// ============ KB: adjacency + closed-form LN + relu + U-dot + softmax =======
__global__ __launch_bounds__(256) void kb_scores(
    const float* __restrict__ a, const float* __restrict__ bp_t, const float* __restrict__ cp_t,
    const float* __restrict__ var_t, const float* __restrict__ nv,
    const float* __restrict__ ma, const float* __restrict__ qa,
    const float* __restrict__ mb, const float* __restrict__ qb,
    const float* __restrict__ mc, const float* __restrict__ qc,
    const float* __restrict__ sq, const float* __restrict__ sk,
    const float* __restrict__ ln_g, const float* __restrict__ ln_b,
    const float* __restrict__ U, const float* __restrict__ ubias,
    const float* __restrict__ b_attn,
    float* __restrict__ attn) {
    const int i = blockIdx.x, b = blockIdx.y;
    const int t = threadIdx.x, j = t & 127, dh = t >> 7;
    __shared__ float Arow[DD];
    __shared__ float Vrow[DD];
    __shared__ float2 lnsm[DD];
    __shared__ __attribute__((aligned(16))) float4 Usm[DD][2];
    __shared__ float skm[HH * NN];
    __shared__ float sc[HH][132];
    __shared__ float accred[128][9];
    __shared__ float redc[128][2];
    __shared__ float redv[128][2];

    Arow[t] = (i >= 1) ? a[((size_t)b * SS + i - 1) * DD + t] : 0.f;
    Vrow[t] = nv[((size_t)b * NN + i) * DD + t];
    { float2 g; g.x = ln_g[t]; g.y = ln_b[t]; lnsm[t] = g; }
    Usm[t][0] = *(const float4*)&U[t * HH];
    Usm[t][1] = *(const float4*)&U[t * HH + 4];
    for (int e = t; e < HH * NN; e += 256) skm[e] = sk[(size_t)b * (HH * NN) + e];
    __syncthreads();

    // pass 1: cross = a_i . b'_j ; dvv = nv_i . nv_j
    float cr = 0.f, dv = 0.f;
    if (i >= 1) {
        const float* bc = bp_t + ((size_t)b * DD + dh * 128) * SS;
        const float* vc = var_t + ((size_t)b * DD + dh * 128) * SS;
#pragma unroll 8
        for (int dd = 0; dd < 128; dd++) {
            float Bv = bc[(size_t)dd * SS + j];
            float Vv = vc[(size_t)dd * SS + j];
            cr = fmaf(Arow[dh * 128 + dd], Bv, cr);
            dv = fmaf(Vrow[dh * 128 + dd], Vv, dv);
        }
    }
    redc[j][dh] = cr; redv[j][dh] = dv;
    __syncthreads();
    cr = redc[j][0] + redc[j][1];
    dv = redv[j][0] + redv[j][1];
    float rs, nm, mk, pen;
    if (i == 0) {
        float mu = mc[b * SS + j], q2 = qc[b * SS + j];
        rs = rsqrtf(q2 - mu * mu + LN_EPS); nm = -mu * rs; mk = 1.f; pen = 0.f;
    } else {
        float muA = ma[b * SS + i - 1], qA = qa[b * SS + i - 1];
        float muB = mb[b * SS + j],     qB = qb[b * SS + j];
        float mu = muA + muB;
        float var = qA + qB + 2.f * cr * (1.f / DD) - mu * mu;
        rs = rsqrtf(var + LN_EPS); nm = -mu * rs;
        mk = ((i - 1) != j && dv > 0.f) ? 1.f : 0.f;
        pen = (mk == 0.f) ? -1e9f : 0.f;
    }

    // pass 2: LN + relu + U-dot (8 heads)
    float acc[HH];
#pragma unroll
    for (int h = 0; h < HH; h++) acc[h] = 0.f;
    {
        const float* Bp = ((i == 0) ? cp_t : bp_t) + ((size_t)b * DD + dh * 128) * SS;
#pragma unroll 4
        for (int dd = 0; dd < 128; dd++) {
            const int d2 = dh * 128 + dd;
            float Bv = Bp[(size_t)dd * SS + j];
            float pre = Arow[d2] + Bv;
            float y = fmaf(pre, rs, nm);
            float2 gb = lnsm[d2];
            y = fmaf(y, gb.x, gb.y);
            float rr = fmaxf(y, 0.f);
            float4 u0 = Usm[d2][0], u1 = Usm[d2][1];
            acc[0] = fmaf(rr, u0.x, acc[0]); acc[1] = fmaf(rr, u0.y, acc[1]);
            acc[2] = fmaf(rr, u0.z, acc[2]); acc[3] = fmaf(rr, u0.w, acc[3]);
            acc[4] = fmaf(rr, u1.x, acc[4]); acc[5] = fmaf(rr, u1.y, acc[5]);
            acc[6] = fmaf(rr, u1.z, acc[6]); acc[7] = fmaf(rr, u1.w, acc[7]);
        }
    }
    if (dh == 1) {
#pragma unroll
        for (int h = 0; h < HH; h++) accred[j][h] = acc[h];
    }
    __syncthreads();
    if (dh == 0) {
        const float ba = b_attn[0];
#pragma unroll
        for (int h = 0; h < HH; h++) {
            float af = acc[h] + accred[j][h];
            float sqv = sq[(size_t)b * (HH * NN) + h * NN + i];
            sc[h][1 + j] = sqv + skm[h * NN + 1 + j] + (af + ubias[h]) * mk + ba + pen;
        }
        if (j == 0) {
#pragma unroll
            for (int h = 0; h < HH; h++)
                sc[h][0] = sq[(size_t)b * (HH * NN) + h * NN + i] + skm[h * NN] + ba - 1e9f;
        }
    }
    __syncthreads();

    // softmax + write: 32 lanes per head row
    {
        const int h = t >> 5, l = t & 31;
        float m = -INFINITY;
        for (int jj = l; jj < NN; jj += 32) m = fmaxf(m, sc[h][jj]);
#pragma unroll
        for (int o = 16; o; o >>= 1) m = fmaxf(m, __shfl_xor(m, o, 32));
        float s = 0.f;
        for (int jj = l; jj < NN; jj += 32) { float e = __expf(sc[h][jj] - m); sc[h][jj] = e; s += e; }
#pragma unroll
        for (int o = 16; o; o >>= 1) s += __shfl_xor(s, o, 32);
        float inv = 1.f / s;
        float* arow = attn + (((size_t)b * HH + h) * NN + i) * NN;
        for (int jj = l; jj < NN; jj += 32) arow[jj] = sc[h][jj] * inv;
    }
}

// ============ KC: ctx = attn@v ; out = ctx@W_o + b_o ========================
__global__ __launch_bounds__(512) void kc_out(
    const float* __restrict__ attn, const float* __restrict__ v,
    const float* __restrict__ W_o, const float* __restrict__ b_o,
    float* __restrict__ out) {
    const int b = blockIdx.y, i0 = blockIdx.x * 4;
    const int t = threadIdx.x;
    __shared__ float ar[4][HH * 133];   // h*133 + j (pad 129->133)
    __shared__ float red[2][4][DD];
    __shared__ float csm[4][DD];
    for (int e = t; e < 4 * HH * NN; e += 512) {
        int il = e / (HH * NN), r = e - il * (HH * NN);
        int h = r / NN, jj = r - h * NN;
        int i = i0 + il; if (i > NN - 1) i = NN - 1;
        ar[il][h * 133 + jj] = attn[(((size_t)b * HH + h) * NN + i) * NN + jj];
    }
    __syncthreads();
    {   // ctx: thread (d, j-half)
        const int d = t & 255, jh = t >> 8;
        const int h = d >> 5;
        float cacc[4] = {0.f, 0.f, 0.f, 0.f};
        const int j0 = jh * 65, j1 = (jh == 0) ? 65 : NN;
        for (int jj = j0; jj < j1; jj++) {
            float vv = v[((size_t)b * NN + jj) * DD + d];
            cacc[0] = fmaf(ar[0][h * 133 + jj], vv, cacc[0]);
            cacc[1] = fmaf(ar[1][h * 133 + jj], vv, cacc[1]);
            cacc[2] = fmaf(ar[2][h * 133 + jj], vv, cacc[2]);
            cacc[3] = fmaf(ar[3][h * 133 + jj], vv, cacc[3]);
        }
#pragma unroll
        for (int il = 0; il < 4; il++) red[jh][il][d] = cacc[il];
    }
    __syncthreads();
    for (int e = t; e < 4 * DD; e += 512) {
        int il = e >> 8, d = e & 255;
        csm[il][d] = red[0][il][d] + red[1][il][d];
    }
    __syncthreads();
    {   // out proj: thread (d2, k-half)
        const int d2 = t & 255, kh = t >> 8;
        float o[4] = {0.f, 0.f, 0.f, 0.f};
        const int kb = kh * 128;
#pragma unroll 8
        for (int k = kb; k < kb + 128; k++) {
            float w = W_o[(size_t)k * DD + d2];
            o[0] = fmaf(csm[0][k], w, o[0]); o[1] = fmaf(csm[1][k], w, o[1]);
            o[2] = fmaf(csm[2][k], w, o[2]); o[3] = fmaf(csm[3][k], w, o[3]);
        }
#pragma unroll
        for (int il = 0; il < 4; il++) red[kh][il][d2] = o[il];
    }
    __syncthreads();
    for (int e = t; e < 4 * DD; e += 512) {
        int il = e >> 8, d = e & 255;
        int i = i0 + il;
        if (i < NN)
            out[((size_t)b * NN + i) * DD + d] = red[0][il][d] + red[1][il][d] + b_o[d];
    }
}

extern "C" void kernel_launch(void* const* d_in, const int* in_sizes, int n_in,
                              void* d_out, int out_size, void* d_ws, size_t ws_size,
                              hipStream_t stream) {
    const float* desc   = (const float*)d_in[0];
    const float* nv     = (const float*)d_in[1];
    const float* W_gt   = (const float*)d_in[2];
    const float* b_gt   = (const float*)d_in[3];
    // d_in[4] topo_bias unused: sigmoid(x)>0 always, so adjacency sign = sample_sim sign
    const float* W_q    = (const float*)d_in[5];
    const float* b_q    = (const float*)d_in[6];
    const float* W_k    = (const float*)d_in[7];
    const float* b_k    = (const float*)d_in[8];
    const float* W_v    = (const float*)d_in[9];
    const float* b_v    = (const float*)d_in[10];
    const float* W_e1   = (const float*)d_in[11];
    const float* b_e1   = (const float*)d_in[12];
    const float* ln_g   = (const float*)d_in[13];
    const float* ln_b   = (const float*)d_in[14];
    const float* W_e2   = (const float*)d_in[15];
    const float* b_e2   = (const float*)d_in[16];
    const float* w_attn = (const float*)d_in[17];
    const float* b_attn = (const float*)d_in[18];
    const float* W_o    = (const float*)d_in[19];
    const float* b_o    = (const float*)d_in[20];

    float* ws   = (float*)d_ws;
    float* a    = ws + OFF_A;
    float* bp_t = ws + OFF_BPT;
    float* cp_t = ws + OFF_CPT;
    float* vart = ws + OFF_VART;
    float* v    = ws + OFF_V;
    float* sq   = ws + OFF_SQ;
    float* sk   = ws + OFF_SK;
    float* ma   = ws + OFF_MA;
    float* qa   = ws + OFF_QA;
    float* mb   = ws + OFF_MB;
    float* qb   = ws + OFF_QB;
    float* mc   = ws + OFF_MC;
    float* qc   = ws + OFF_QC;
    float* U    = ws + OFF_U;
    float* ub   = ws + OFF_UB;

    float* out  = (float*)d_out;
    float* attn = (float*)d_out + (size_t)BB * NN * DD;

    // KA: 256 (projA) + 520 (qkv) + 64 (U-fold) = 840 blocks
    ka_all<<<dim3(840), dim3(512), 0, stream>>>(
        desc, nv, W_gt, b_gt, W_e1, b_e1, W_q, b_q, W_k, b_k, W_v, b_v,
        W_e2, b_e2, w_attn,
        a, bp_t, cp_t, vart, v, sq, sk, ma, qa, mb, qb, mc, qc, U, ub);
    kb_scores<<<dim3(NN, BB), dim3(256), 0, stream>>>(
        a, bp_t, cp_t, vart, nv, ma, qa, mb, qb, mc, qc, sq, sk,
        ln_g, ln_b, U, ub, b_attn, attn);
    kc_out<<<dim3((NN + 3) / 4, BB), dim3(512), 0, stream>>>(attn, v, W_o, b_o, out);
}